// Round 4
// baseline (332.206 us; speedup 1.0000x reference)
//
#include <hip/hip_runtime.h>

typedef __bf16 bf16;
typedef __attribute__((ext_vector_type(8))) __bf16 bf16x8;
typedef __attribute__((ext_vector_type(2))) __bf16 bf16x2;
typedef __attribute__((ext_vector_type(4))) float f32x4;
typedef __attribute__((ext_vector_type(8))) unsigned short ushort8;   // 16B
typedef __attribute__((ext_vector_type(4))) unsigned short ushort4v;  // 8B

__device__ __forceinline__ unsigned short f2bf(float f) {
    union { float f; unsigned int u; } v; v.f = f;
    unsigned int u = v.u;
    return (unsigned short)((u + 0x7fffu + ((u >> 16) & 1u)) >> 16);
}

// packed f32x2 -> bf16x2 (RTNE). HW instr on gfx950 if available.
#if __has_builtin(__builtin_amdgcn_cvt_pk_bf16_f32)
__device__ __forceinline__ unsigned int pk2bf(float a, float b) {
    union { bf16x2 v; unsigned int u; } c;
    c.v = __builtin_amdgcn_cvt_pk_bf16_f32(a, b);
    return c.u;
}
#else
__device__ __forceinline__ unsigned int pk2bf(float a, float b) {
    return (unsigned int)f2bf(a) | ((unsigned int)f2bf(b) << 16);
}
#endif

__device__ __forceinline__ f32x4 mfma16(bf16x8 a, bf16x8 b, f32x4 c) {
    return __builtin_amdgcn_mfma_f32_16x16x32_bf16(a, b, c, 0, 0, 0);
}

// ---------------- fused fp32 -> bf16 convert (x, w_qkv, w_proj in one launch) ----------------
__global__ void cvt3_f32_bf16(const float* __restrict__ x, const float* __restrict__ wq,
                              const float* __restrict__ wp,
                              unsigned short* __restrict__ xb, unsigned short* __restrict__ wqb,
                              unsigned short* __restrict__ wpb) {
    int i = blockIdx.x * 256 + threadIdx.x;   // float4 index
    const float* in; unsigned short* out; int base;
    if (i < 1572864)      { in = x;  out = xb;  base = i; }
    else if (i < 2015232) { in = wq; out = wqb; base = i - 1572864; }
    else if (i < 2162688) { in = wp; out = wpb; base = i - 2015232; }
    else return;
    float4 f = reinterpret_cast<const float4*>(in)[base];
    union { ushort4v v; unsigned int u[2]; } o;
    o.u[0] = pk2bf(f.x, f.y);
    o.u[1] = pk2bf(f.z, f.w);
    reinterpret_cast<ushort4v*>(out)[base] = o.v;
}

// ---------------- QKV GEMM: [8192x768] x [2304x768]^T, scatter to Q,K,Vt ----------------
// Q is pre-scaled by SCALE*log2(e) so attention can use exp2 directly.
__global__ __launch_bounds__(256) void qkv_gemm(const unsigned short* __restrict__ A,
                                                const unsigned short* __restrict__ W,
                                                unsigned short* __restrict__ Qg,
                                                unsigned short* __restrict__ Kg,
                                                unsigned short* __restrict__ Vtg) {
    __shared__ __align__(16) unsigned short As[128 * 40];
    __shared__ __align__(16) unsigned short Bs[128 * 40];
    const int t = threadIdx.x;
    const int w = t >> 6, l = t & 63;
    const int wm = (w >> 1) * 64, wn = (w & 1) * 64;
    const int lr = l & 15, lq = l >> 4;
    const int m0 = blockIdx.y * 128, n0 = blockIdx.x * 128;
    f32x4 acc[4][4] = {};
    for (int k0 = 0; k0 < 768; k0 += 32) {
        __syncthreads();
#pragma unroll
        for (int i = 0; i < 2; ++i) {
            int v = t + i * 256;
            int r = v >> 2, c8 = (v & 3) * 8;
            *reinterpret_cast<ushort8*>(&As[r * 40 + c8]) =
                *reinterpret_cast<const ushort8*>(&A[(m0 + r) * 768 + k0 + c8]);
            *reinterpret_cast<ushort8*>(&Bs[r * 40 + c8]) =
                *reinterpret_cast<const ushort8*>(&W[(n0 + r) * 768 + k0 + c8]);
        }
        __syncthreads();
        bf16x8 af[4], bfr[4];
#pragma unroll
        for (int mt = 0; mt < 4; ++mt)
            af[mt] = *reinterpret_cast<const bf16x8*>(&As[(wm + mt * 16 + lr) * 40 + lq * 8]);
#pragma unroll
        for (int nt = 0; nt < 4; ++nt)
            bfr[nt] = *reinterpret_cast<const bf16x8*>(&Bs[(wn + nt * 16 + lr) * 40 + lq * 8]);
#pragma unroll
        for (int mt = 0; mt < 4; ++mt)
#pragma unroll
            for (int nt = 0; nt < 4; ++nt)
                acc[mt][nt] = mfma16(af[mt], bfr[nt], acc[mt][nt]);
    }
    // epilogue: Q scaled by 96^-0.5 * log2(e) = 0.14724444; V transposed
#pragma unroll
    for (int nt = 0; nt < 4; ++nt) {
        int gn = n0 + wn + nt * 16 + lr;
        int tsel = gn / 768, rem = gn - tsel * 768;
        int h = rem / 96, d = rem - h * 96;
#pragma unroll
        for (int mt = 0; mt < 4; ++mt) {
#pragma unroll
            for (int r = 0; r < 4; ++r) {
                int gm = m0 + wm + mt * 16 + lq * 4 + r;
                int b = gm >> 12, n = gm & 4095;
                int bh = b * 8 + h;
                float val = acc[mt][nt][r];
                if (tsel == 0)      Qg[(bh * 4096 + n) * 96 + d] = f2bf(val * 0.14724444f);
                else if (tsel == 1) Kg[(bh * 4096 + n) * 96 + d] = f2bf(val);
                else                Vtg[(bh * 96 + d) * 4096 + n] = f2bf(val);
            }
        }
    }
}

// ---------------- Flash attention (no-max streaming softmax, exp2 domain) ----------------
// 512 threads = 8 waves in 4(rows)x2(keys). Br=128, Tc=64, D=96.
// Wave (wr,wk): q-rows wr*32..+31, keys wk*32..+31 of each 64-key tile.
// Key-split partials are linear (no-max softmax) -> cross-wave LDS reduce at end.
// LDS aliased: Qs dead after frag hoist; Ks/Vs/Ps overlay it. 45.6 KB -> 2 blocks/CU, 16 waves/CU.
__global__ __launch_bounds__(512, 4) void attn_kernel(const unsigned short* __restrict__ Qg,
                                                      const unsigned short* __restrict__ Kg,
                                                      const unsigned short* __restrict__ Vtg,
                                                      unsigned short* __restrict__ Og) {
    __shared__ __align__(16) char lds[45568];
    unsigned short* Qs = (unsigned short*)lds;              // 128 x 96   (prologue only)
    unsigned short* Ks = (unsigned short*)lds;              // 64 x 104   (aliases Qs)
    unsigned short* Vs = (unsigned short*)(lds + 13312);    // 96 x 72
    unsigned short* Ps = (unsigned short*)(lds + 27136);    // 128 x 72
    float*          red = (float*)lds;                      // epilogue reduce buffer

    const int t = threadIdx.x;
    const int w = t >> 6, l = t & 63;
    const int wr = w >> 1, wk = w & 1;
    const int lr = l & 15, lq = l >> 4;
    const int bh = blockIdx.y;
    const int q0 = blockIdx.x * 128;
    const int qbase = bh * 4096 * 96;

    // stage Q tile (1536 ushort8 over 512 threads)
#pragma unroll
    for (int i = 0; i < 3; ++i) {
        int v = t + i * 512;
        int r = v / 12, c8 = (v % 12) * 8;
        *reinterpret_cast<ushort8*>(&Qs[r * 96 + c8]) =
            *reinterpret_cast<const ushort8*>(&Qg[qbase + (q0 + r) * 96 + c8]);
    }
    __syncthreads();
    // hoist Q fragments (rows of Q, used as B-operand for S^T). Qs dead afterwards.
    bf16x8 aq[2][3];
#pragma unroll
    for (int mt = 0; mt < 2; ++mt)
#pragma unroll
        for (int kq = 0; kq < 3; ++kq)
            aq[mt][kq] = *reinterpret_cast<const bf16x8*>(&Qs[(wr * 32 + mt * 16 + lr) * 96 + kq * 32 + lq * 8]);

    bf16x8 vones;
#pragma unroll
    for (int i = 0; i < 8; ++i) vones[i] = (__bf16)1.0f;

    f32x4 acc[2][6] = {};
    f32x4 acc_l[2] = {};

    for (int kv0 = 0; kv0 < 4096; kv0 += 64) {
        __syncthreads();   // protects Ks/Vs restage vs prev iter reads (and Qs hoist on iter 0)
        // stage K (64x96 -> 768 v8) and Vt (96x64 -> 768 v8) with 512 threads
#pragma unroll
        for (int j = 0; j < 3; ++j) {
            int v = t + j * 512;
            if (v < 768) {
                int r = v / 12, c8 = (v % 12) * 8;
                *reinterpret_cast<ushort8*>(&Ks[r * 104 + c8]) =
                    *reinterpret_cast<const ushort8*>(&Kg[qbase + (kv0 + r) * 96 + c8]);
            } else {
                int u = v - 768;
                int d = u >> 3, c8v = (u & 7) * 8;
                *reinterpret_cast<ushort8*>(&Vs[d * 72 + c8v]) =
                    *reinterpret_cast<const ushort8*>(&Vtg[(bh * 96 + d) * 4096 + kv0 + c8v]);
            }
        }
        __syncthreads();
        // S^T = K Q^T: s[mt][ntl][r] = S^T[key = wk*32+ntl*16+lq*4+r][qrow = wr*32+mt*16+lr]
        f32x4 s[2][2] = {};
#pragma unroll
        for (int kq = 0; kq < 3; ++kq) {
            bf16x8 bk[2];
#pragma unroll
            for (int ntl = 0; ntl < 2; ++ntl)
                bk[ntl] = *reinterpret_cast<const bf16x8*>(&Ks[(wk * 32 + ntl * 16 + lr) * 104 + kq * 32 + lq * 8]);
#pragma unroll
            for (int mt = 0; mt < 2; ++mt)
#pragma unroll
                for (int ntl = 0; ntl < 2; ++ntl)
                    s[mt][ntl] = mfma16(bk[ntl], aq[mt][kq], s[mt][ntl]);
        }
        // p = exp2(s); pack 4 consecutive keys -> one b64 store (wave-private Ps region)
#pragma unroll
        for (int mt = 0; mt < 2; ++mt) {
#pragma unroll
            for (int ntl = 0; ntl < 2; ++ntl) {
                union { ushort4v v; unsigned int u[2]; } pk;
                pk.u[0] = pk2bf(__builtin_amdgcn_exp2f(s[mt][ntl][0]),
                                __builtin_amdgcn_exp2f(s[mt][ntl][1]));
                pk.u[1] = pk2bf(__builtin_amdgcn_exp2f(s[mt][ntl][2]),
                                __builtin_amdgcn_exp2f(s[mt][ntl][3]));
                *reinterpret_cast<ushort4v*>(
                    &Ps[(wr * 32 + mt * 16 + lr) * 72 + wk * 32 + ntl * 16 + lq * 4]) = pk.v;
            }
        }
        // no barrier: this wave reads exactly the P block it wrote (rows wr*32.., keys wk*32..)
        // O += P V over this wave's 32 keys; l += P * ones
        bf16x8 ap[2];
#pragma unroll
        for (int mt = 0; mt < 2; ++mt)
            ap[mt] = *reinterpret_cast<const bf16x8*>(&Ps[(wr * 32 + mt * 16 + lr) * 72 + wk * 32 + lq * 8]);
#pragma unroll
        for (int dt = 0; dt < 6; ++dt) {
            bf16x8 bv = *reinterpret_cast<const bf16x8*>(&Vs[(dt * 16 + lr) * 72 + wk * 32 + lq * 8]);
#pragma unroll
            for (int mt = 0; mt < 2; ++mt)
                acc[mt][dt] = mfma16(ap[mt], bv, acc[mt][dt]);
        }
#pragma unroll
        for (int mt = 0; mt < 2; ++mt)
            acc_l[mt] = mfma16(ap[mt], vones, acc_l[mt]);
    }

    // ---- cross-wave reduce over wk pairs (two passes, fp32, stride 36 floats = 16B aligned) ----
    const int base = (wr * 64 + l) * 36;
    __syncthreads();
    if (wk == 1) {
#pragma unroll
        for (int mt = 0; mt < 2; ++mt) {
#pragma unroll
            for (int dt = 0; dt < 3; ++dt)
                *reinterpret_cast<f32x4*>(&red[base + (mt * 3 + dt) * 4]) = acc[mt][dt];
            *reinterpret_cast<f32x4*>(&red[base + 24 + mt * 4]) = acc_l[mt];
        }
    }
    __syncthreads();
    if (wk == 0) {
#pragma unroll
        for (int mt = 0; mt < 2; ++mt) {
#pragma unroll
            for (int dt = 0; dt < 3; ++dt)
                acc[mt][dt] += *reinterpret_cast<const f32x4*>(&red[base + (mt * 3 + dt) * 4]);
            acc_l[mt] += *reinterpret_cast<const f32x4*>(&red[base + 24 + mt * 4]);
        }
    }
    __syncthreads();
    if (wk == 1) {
#pragma unroll
        for (int mt = 0; mt < 2; ++mt)
#pragma unroll
            for (int dt = 3; dt < 6; ++dt)
                *reinterpret_cast<f32x4*>(&red[base + (mt * 3 + dt - 3) * 4]) = acc[mt][dt];
    }
    __syncthreads();
    if (wk == 0) {
#pragma unroll
        for (int mt = 0; mt < 2; ++mt)
#pragma unroll
            for (int dt = 3; dt < 6; ++dt)
                acc[mt][dt] += *reinterpret_cast<const f32x4*>(&red[base + (mt * 3 + dt - 3) * 4]);
        // normalize + write attn_out[b][n][h*96+d] (bf16 scratch)
        const int b = bh >> 3, h = bh & 7;
#pragma unroll
        for (int mt = 0; mt < 2; ++mt) {
#pragma unroll
            for (int r = 0; r < 4; ++r) {
                float inv = 1.f / acc_l[mt][r];
                int n = q0 + wr * 32 + mt * 16 + lq * 4 + r;
                int rowoff = (b * 4096 + n) * 768 + h * 96;
#pragma unroll
                for (int dt = 0; dt < 6; ++dt)
                    Og[rowoff + dt * 16 + lr] = f2bf(acc[mt][dt][r] * inv);
            }
        }
    }
}

// ---------------- proj GEMM: [8192x768] x [768x768]^T -> FP32 out ----------------
__global__ __launch_bounds__(256) void proj_gemm(const unsigned short* __restrict__ A,
                                                 const unsigned short* __restrict__ W,
                                                 float* __restrict__ out) {
    __shared__ __align__(16) unsigned short As[128 * 40];
    __shared__ __align__(16) unsigned short Bs[128 * 40];
    const int t = threadIdx.x;
    const int w = t >> 6, l = t & 63;
    const int wm = (w >> 1) * 64, wn = (w & 1) * 64;
    const int lr = l & 15, lq = l >> 4;
    const int m0 = blockIdx.y * 128, n0 = blockIdx.x * 128;
    f32x4 acc[4][4] = {};
    for (int k0 = 0; k0 < 768; k0 += 32) {
        __syncthreads();
#pragma unroll
        for (int i = 0; i < 2; ++i) {
            int v = t + i * 256;
            int r = v >> 2, c8 = (v & 3) * 8;
            *reinterpret_cast<ushort8*>(&As[r * 40 + c8]) =
                *reinterpret_cast<const ushort8*>(&A[(m0 + r) * 768 + k0 + c8]);
            *reinterpret_cast<ushort8*>(&Bs[r * 40 + c8]) =
                *reinterpret_cast<const ushort8*>(&W[(n0 + r) * 768 + k0 + c8]);
        }
        __syncthreads();
        bf16x8 af[4], bfr[4];
#pragma unroll
        for (int mt = 0; mt < 4; ++mt)
            af[mt] = *reinterpret_cast<const bf16x8*>(&As[(wm + mt * 16 + lr) * 40 + lq * 8]);
#pragma unroll
        for (int nt = 0; nt < 4; ++nt)
            bfr[nt] = *reinterpret_cast<const bf16x8*>(&Bs[(wn + nt * 16 + lr) * 40 + lq * 8]);
#pragma unroll
        for (int mt = 0; mt < 4; ++mt)
#pragma unroll
            for (int nt = 0; nt < 4; ++nt)
                acc[mt][nt] = mfma16(af[mt], bfr[nt], acc[mt][nt]);
    }
#pragma unroll
    for (int nt = 0; nt < 4; ++nt) {
        int gn = n0 + wn + nt * 16 + lr;
#pragma unroll
        for (int mt = 0; mt < 4; ++mt) {
#pragma unroll
            for (int r = 0; r < 4; ++r) {
                int gm = m0 + wm + mt * 16 + lq * 4 + r;
                out[gm * 768 + gn] = acc[mt][nt][r];
            }
        }
    }
}

extern "C" void kernel_launch(void* const* d_in, const int* in_sizes, int n_in,
                              void* d_out, int out_size, void* d_ws, size_t ws_size,
                              hipStream_t stream) {
    const float* x     = (const float*)d_in[0];   // [2,4096,768] fp32
    const float* wqkv  = (const float*)d_in[1];   // [2304,768] fp32
    const float* wproj = (const float*)d_in[2];   // [768,768] fp32
    float* out = (float*)d_out;                   // fp32 [2,4096,768]
    char* ws = (char*)d_ws;
    unsigned short* xb     = (unsigned short*)(ws);             // 12582912
    unsigned short* wqkvb  = (unsigned short*)(ws + 12582912);  // 3538944
    unsigned short* wprojb = (unsigned short*)(ws + 16121856);  // 1179648
    unsigned short* Qg     = (unsigned short*)(ws + 17301504);  // [B,H,N,D]
    unsigned short* Kg     = (unsigned short*)(ws + 29884416);  // [B,H,N,D]
    unsigned short* Vtg    = (unsigned short*)(ws + 42467328);  // [B,H,D,N]
    unsigned short* attnb  = xb;                                // reuse: [B,N,C] bf16

    cvt3_f32_bf16<<<8448, 256, 0, stream>>>(x, wqkv, wproj, xb, wqkvb, wprojb);
    qkv_gemm<<<dim3(18, 64), 256, 0, stream>>>(xb, wqkvb, Qg, Kg, Vtg);
    attn_kernel<<<dim3(32, 16), 512, 0, stream>>>(Qg, Kg, Vtg, attnb);
    proj_gemm<<<dim3(6, 64), 256, 0, stream>>>(attnb, wprojb, out);
}